// Round 1
// baseline (340.132 us; speedup 1.0000x reference)
//
#include <hip/hip_runtime.h>

// Problem constants (from reference): image (8,256,64,64) f32, boxes (1000,4) f32,
// box_ind (1000,) i32, output (1000,256,14,14) f32.
constexpr int CROP_H = 14;
constexpr int CROP_W = 14;
constexpr int IMG_C  = 256;
constexpr int IMG_H  = 64;
constexpr int IMG_W  = 64;

__global__ __launch_bounds__(256) void CropAndResize_5669356832751_kernel(
    const float* __restrict__ image,
    const float* __restrict__ boxes,
    const int*   __restrict__ box_ind,
    float* __restrict__ out,
    int total)
{
    int idx = blockIdx.x * blockDim.x + threadIdx.x;
    if (idx >= total) return;

    // Decompose flat output index [N, C, CROP_H, CROP_W]
    int x = idx % CROP_W;
    int t = idx / CROP_W;
    int y = t % CROP_H;
    t /= CROP_H;
    int c = t % IMG_C;
    int n = t / IMG_C;

    // Box params — wave-uniform across >=196 consecutive threads → scalarized loads
    float y1 = boxes[n * 4 + 0];
    float x1 = boxes[n * 4 + 1];
    float y2 = boxes[n * 4 + 2];
    float x2 = boxes[n * 4 + 3];
    int   b  = box_ind[n];

    const float h_scale = (y2 - y1) * (float)(IMG_H - 1) / (float)(CROP_H - 1);
    const float w_scale = (x2 - x1) * (float)(IMG_W - 1) / (float)(CROP_W - 1);

    float in_y = y1 * (float)(IMG_H - 1) + (float)y * h_scale;
    float in_x = x1 * (float)(IMG_W - 1) + (float)x * w_scale;

    bool oob = (in_y < 0.0f) || (in_y > (float)(IMG_H - 1)) ||
               (in_x < 0.0f) || (in_x > (float)(IMG_W - 1));

    float top_f  = floorf(in_y);
    float left_f = floorf(in_x);
    float y_lerp = in_y - top_f;
    float x_lerp = in_x - left_f;

    int ti = (int)fminf(fmaxf(top_f,        0.0f), (float)(IMG_H - 1));
    int bi = (int)fminf(fmaxf(top_f + 1.0f, 0.0f), (float)(IMG_H - 1));
    int li = (int)fminf(fmaxf(left_f,        0.0f), (float)(IMG_W - 1));
    int ri = (int)fminf(fmaxf(left_f + 1.0f, 0.0f), (float)(IMG_W - 1));

    const float* plane = image + ((size_t)b * IMG_C + c) * (size_t)(IMG_H * IMG_W);
    float tl = plane[ti * IMG_W + li];
    float tr = plane[ti * IMG_W + ri];
    float bl = plane[bi * IMG_W + li];
    float br = plane[bi * IMG_W + ri];

    float top_v = tl + (tr - tl) * x_lerp;
    float bot_v = bl + (br - bl) * x_lerp;
    float val   = top_v + (bot_v - top_v) * y_lerp;

    out[idx] = oob ? 0.0f : val;
}

extern "C" void kernel_launch(void* const* d_in, const int* in_sizes, int n_in,
                              void* d_out, int out_size, void* d_ws, size_t ws_size,
                              hipStream_t stream) {
    const float* image   = (const float*)d_in[0];
    const float* boxes   = (const float*)d_in[1];
    const int*   box_ind = (const int*)d_in[2];
    float* out = (float*)d_out;

    int total = out_size;  // 1000 * 256 * 14 * 14
    int block = 256;
    int grid  = (total + block - 1) / block;
    CropAndResize_5669356832751_kernel<<<grid, block, 0, stream>>>(
        image, boxes, box_ind, out, total);
}

// Round 2
// 313.457 us; speedup vs baseline: 1.0851x; 1.0851x over previous
//
#include <hip/hip_runtime.h>

// image (8,256,64,64) f32, boxes (1000,4) f32, box_ind (1000,) i32
// out (1000,256,14,14) f32
constexpr int CROP_H = 14;
constexpr int CROP_W = 14;
constexpr int PIX    = CROP_H * CROP_W;   // 196
constexpr int IMG_C  = 256;
constexpr int IMG_H  = 64;
constexpr int IMG_W  = 64;
constexpr int N_BOX  = 1000;
constexpr int CPT    = 64;                // channels per thread
constexpr int NCHUNK = IMG_C / CPT;       // 4

__global__ __launch_bounds__(256) void CropAndResize_5669356832751_kernel(
    const float* __restrict__ image,
    const float* __restrict__ boxes,
    const int*   __restrict__ box_ind,
    float* __restrict__ out)
{
    int tid = blockIdx.x * 256 + threadIdx.x;
    if (tid >= N_BOX * PIX) return;

    // tid -> (n, p=(y,x)); lanes consecutive in p => coalesced stores
    int n = tid / PIX;
    int p = tid - n * PIX;
    int y = p / CROP_W;
    int x = p - y * CROP_W;
    int c0 = blockIdx.y * CPT;

    float y1 = boxes[4 * n + 0];
    float x1 = boxes[4 * n + 1];
    float y2 = boxes[4 * n + 2];
    float x2 = boxes[4 * n + 3];
    int   b  = box_ind[n];

    const float hs = (y2 - y1) * (63.0f / 13.0f);
    const float ws = (x2 - x1) * (63.0f / 13.0f);
    float in_y = y1 * 63.0f + (float)y * hs;
    float in_x = x1 * 63.0f + (float)x * ws;

    bool oob = (in_y < 0.0f) | (in_y > 63.0f) | (in_x < 0.0f) | (in_x > 63.0f);

    float tf = floorf(in_y);
    float lf = floorf(in_x);
    int ti = (int)fminf(fmaxf(tf, 0.0f), 63.0f);
    int li = (int)fminf(fmaxf(lf, 0.0f), 63.0f);

    // Shift 2x2 window so all 4 taps are in-bounds at fixed offsets:
    // rows {row0,row0+1}, cols {col0,col0+1}. Effective lerp measured from
    // the window origin reproduces the clamped-tap semantics exactly for
    // in-bounds samples (ti==63 -> in_y==63 -> lerp_eff==1 selects row 63).
    int row0 = min(ti, 62);
    int col0 = min(li, 62);
    float yl = fminf(fmaxf(in_y, 0.0f), 63.0f) - (float)row0;
    float xl = fminf(fmaxf(in_x, 0.0f), 63.0f) - (float)col0;

    // Bilinear weights with OOB mask folded in (OOB -> all zero -> val 0)
    float m    = oob ? 0.0f : 1.0f;
    float omxl = 1.0f - xl;
    float omyl = 1.0f - yl;
    float w00 = omxl * omyl * m;
    float w01 = xl   * omyl * m;
    float w10 = omxl * yl   * m;
    float w11 = xl   * yl   * m;

    const float* src = image + ((size_t)b * IMG_C + c0) * (size_t)(IMG_H * IMG_W)
                             + row0 * IMG_W + col0;
    float* dst = out + ((size_t)n * IMG_C + c0) * (size_t)PIX + p;

#pragma unroll 4
    for (int c = 0; c < CPT; ++c) {
        float v00 = src[0];
        float v01 = src[1];
        float v10 = src[IMG_W];
        float v11 = src[IMG_W + 1];
        float v = v00 * w00 + v01 * w01 + v10 * w10 + v11 * w11;
        *dst = v;
        src += IMG_H * IMG_W;
        dst += PIX;
    }
}

extern "C" void kernel_launch(void* const* d_in, const int* in_sizes, int n_in,
                              void* d_out, int out_size, void* d_ws, size_t ws_size,
                              hipStream_t stream) {
    const float* image   = (const float*)d_in[0];
    const float* boxes   = (const float*)d_in[1];
    const int*   box_ind = (const int*)d_in[2];
    float* out = (float*)d_out;

    dim3 grid((N_BOX * PIX + 255) / 256, NCHUNK);
    CropAndResize_5669356832751_kernel<<<grid, 256, 0, stream>>>(
        image, boxes, box_ind, out);
}